// Round 4
// baseline (179.062 us; speedup 1.0000x reference)
//
#include <hip/hip_runtime.h>

// HashEmbedding: out[b,s,:] = embedding[hashed_ids[b,s], :]  (pure gather)
//
// DTYPES — settled by rounds 1-3 forensics:
//  * hashed_ids: int32 (R2's int64 read fused index pairs -> OOB memfault;
//    R1==R3 byte-identical output proves the int32 reads were taken & correct).
//  * embedding / output: FLOAT32 (harness doc: f32 -> const float*). R1/R3's
//    bounded absmax 8.47 = genuine N(0,1) values at wrong flat positions, the
//    signature of copying 2048 B/row (bf16 assumption) instead of 4096 B/row.
//
// Layout: EMBED_DIM = 1024 f32 per row = 4096 B = 256 x uint4 (16 B).
// Thread i copies uint4 chunk i of the flat [B*S, 1024] f32 output:
//   row = i >> 8, col = i & 255. Fully coalesced 16 B/lane loads + stores.

#define ROW_VEC     256     // uint4 chunks per f32 embedding row (1024*4/16)
#define NUM_BUCKETS 10000

__global__ __launch_bounds__(256) void HashEmbedding_46136538693901_kernel(
    const int* __restrict__ hashed_ids,   // [B*S] int32, values in [0, 10000)
    const uint4* __restrict__ emb,        // [NUM_BUCKETS * ROW_VEC]
    uint4* __restrict__ out,              // [B*S * ROW_VEC]
    int n_vec)                            // B*S * ROW_VEC
{
    int i = blockIdx.x * blockDim.x + threadIdx.x;
    if (i >= n_vec) return;
    int row = i >> 8;                     // token index
    int col = i & (ROW_VEC - 1);
    int idx = hashed_ids[row];            // bucket
    if ((unsigned)idx >= (unsigned)NUM_BUCKETS) idx = 0;  // fault guard (no-op normally)
    out[i] = emb[(size_t)idx * ROW_VEC + col];
}

extern "C" void kernel_launch(void* const* d_in, const int* in_sizes, int n_in,
                              void* d_out, int out_size, void* d_ws, size_t ws_size,
                              hipStream_t stream) {
    // setup_inputs dict order: input_ids [B*S] i32 (unused), hashed_ids [B*S] i32,
    // embedding [NUM_BUCKETS*1024] f32.
    const int*   hashed = (const int*)d_in[1];
    const uint4* emb    = (const uint4*)d_in[2];
    uint4*       out    = (uint4*)d_out;

    int n_tokens = in_sizes[1];            // 32768
    int n_vec    = n_tokens * ROW_VEC;     // 8,388,608

    int block = 256;
    int grid  = (n_vec + block - 1) / block;  // 32768
    HashEmbedding_46136538693901_kernel<<<grid, block, 0, stream>>>(hashed, emb, out, n_vec);
}